// Round 1
// baseline (2280.148 us; speedup 1.0000x reference)
//
#include <hip/hip_runtime.h>

#define NN 100000
#define NE 600000
#define D  128
#define C_SRC 0.5f   // (1 - alpha)
#define C_DST 0.5f   // alpha

__global__ __launch_bounds__(256) void k_deg(const int* __restrict__ ei,
                                             int* __restrict__ dout, int* __restrict__ din) {
    int e = blockIdx.x * 256 + threadIdx.x;
    if (e < NE) {
        atomicAdd(&dout[ei[e]], 1);
        atomicAdd(&din[ei[NE + e]], 1);
    }
}

__global__ __launch_bounds__(256) void k_rinv(const int* __restrict__ dout, const int* __restrict__ din,
                                              float* __restrict__ rout, float* __restrict__ rin) {
    int n = blockIdx.x * 256 + threadIdx.x;
    if (n < NN) {
        int a = dout[n], b = din[n];
        rout[n] = a > 0 ? rsqrtf((float)a) : 0.f;
        rin[n]  = b > 0 ? rsqrtf((float)b) : 0.f;
    }
}

// y_s = x @ Ws^T, y_d = x @ Wd^T   (fp32, tiled 64x64, 4x4 per thread)
__global__ __launch_bounds__(256) void k_gemm(const float* __restrict__ x,
                                              const float* __restrict__ Ws,
                                              const float* __restrict__ Wd,
                                              float* __restrict__ ys,
                                              float* __restrict__ yd) {
    __shared__ float xs[64 * 128];    // [r][k] row-major
    __shared__ float wsh[128 * 64];   // [k][jj] k-major, XOR-swizzled
    const float* W = blockIdx.z ? Wd : Ws;
    float*       y = blockIdx.z ? yd : ys;
    const int n0 = blockIdx.x * 64;
    const int c0 = blockIdx.y * 64;
    const int tid = threadIdx.x;

    #pragma unroll
    for (int it = 0; it < 32; ++it) {           // stage x tile (coalesced)
        int idx = it * 256 + tid;
        int r = idx >> 7, k = idx & 127;
        int n = n0 + r;
        xs[idx] = (n < NN) ? x[(size_t)n * D + k] : 0.f;
    }
    #pragma unroll
    for (int it = 0; it < 32; ++it) {           // stage W tile transposed (swizzled vs bank conflicts)
        int idx = it * 256 + tid;
        int jj = idx >> 7, k = idx & 127;
        wsh[k * 64 + (jj ^ ((k & 15) << 2))] = W[(size_t)(c0 + jj) * D + k];
    }
    __syncthreads();

    const int tx = tid & 15, ty = tid >> 4;
    const int cq = tx * 4, r0 = ty * 4;
    float acc[4][4] = {};
    #pragma unroll 4
    for (int k = 0; k < 128; ++k) {
        const float4 wv = *(const float4*)&wsh[k * 64 + (cq ^ ((k & 15) << 2))];
        #pragma unroll
        for (int r = 0; r < 4; ++r) {
            float xv = xs[(r0 + r) * 128 + k];
            acc[r][0] += xv * wv.x;
            acc[r][1] += xv * wv.y;
            acc[r][2] += xv * wv.z;
            acc[r][3] += xv * wv.w;
        }
    }
    #pragma unroll
    for (int r = 0; r < 4; ++r) {
        int n = n0 + r0 + r;
        if (n < NN) {
            float4 v = make_float4(acc[r][0], acc[r][1], acc[r][2], acc[r][3]);
            *(float4*)&y[(size_t)n * D + c0 + cq] = v;
        }
    }
}

__global__ __launch_bounds__(256) void k_init_out(const float* __restrict__ bs,
                                                  const float* __restrict__ bd,
                                                  float* __restrict__ out) {
    int t = blockIdx.x * 256 + threadIdx.x;
    if (t < NN * D) {
        int j = t & 127;
        out[t] = C_SRC * bs[j] + C_DST * bd[j];
    }
}

// per edge: out[row] += (1-a)*w*ys[col], out[col] += a*w*yd[row]; 32 lanes/edge, float4/lane
__global__ __launch_bounds__(256) void k_scatter(const int* __restrict__ ei,
                                                 const float* __restrict__ rout,
                                                 const float* __restrict__ rin,
                                                 const float* __restrict__ ys,
                                                 const float* __restrict__ yd,
                                                 float* __restrict__ out) {
    int t = blockIdx.x * 256 + threadIdx.x;
    int e = t >> 5;
    if (e >= NE) return;
    int l = (t & 31) << 2;
    int row = ei[e];
    int col = ei[NE + e];
    float w  = rout[row] * rin[col];
    float w1 = C_SRC * w;
    float w2 = C_DST * w;
    float4 a = *(const float4*)&ys[(size_t)col * D + l];
    float4 b = *(const float4*)&yd[(size_t)row * D + l];
    float* po = &out[(size_t)row * D + l];
    float* pc = &out[(size_t)col * D + l];
    unsafeAtomicAdd(po + 0, w1 * a.x);
    unsafeAtomicAdd(po + 1, w1 * a.y);
    unsafeAtomicAdd(po + 2, w1 * a.z);
    unsafeAtomicAdd(po + 3, w1 * a.w);
    unsafeAtomicAdd(pc + 0, w2 * b.x);
    unsafeAtomicAdd(pc + 1, w2 * b.y);
    unsafeAtomicAdd(pc + 2, w2 * b.z);
    unsafeAtomicAdd(pc + 3, w2 * b.w);
}

extern "C" void kernel_launch(void* const* d_in, const int* in_sizes, int n_in,
                              void* d_out, int out_size, void* d_ws, size_t ws_size,
                              hipStream_t stream) {
    const float* x  = (const float*)d_in[0];
    const int*   ei = (const int*)d_in[1];
    const float* Ws = (const float*)d_in[2];
    const float* bs = (const float*)d_in[3];
    const float* Wd = (const float*)d_in[4];
    const float* bd = (const float*)d_in[5];
    float* out = (float*)d_out;

    float* ys  = (float*)d_ws;                    // NN*D
    float* yd  = ys + (size_t)NN * D;             // NN*D
    int*   dout = (int*)(yd + (size_t)NN * D);    // NN
    int*   din  = dout + NN;                      // NN
    float* rout = (float*)(din + NN);             // NN
    float* rin  = rout + NN;                      // NN

    hipMemsetAsync(dout, 0, 2 * NN * sizeof(int), stream);
    k_deg<<<(NE + 255) / 256, 256, 0, stream>>>(ei, dout, din);
    k_rinv<<<(NN + 255) / 256, 256, 0, stream>>>(dout, din, rout, rin);
    dim3 gg((NN + 63) / 64, 2, 2);
    k_gemm<<<gg, 256, 0, stream>>>(x, Ws, Wd, ys, yd);
    k_init_out<<<(NN * D + 255) / 256, 256, 0, stream>>>(bs, bd, out);
    k_scatter<<<(NE * 32 + 255) / 256, 256, 0, stream>>>(ei, rout, rin, ys, yd, out);
}

// Round 2
// 483.141 us; speedup vs baseline: 4.7194x; 4.7194x over previous
//
#include <hip/hip_runtime.h>

#define NN 100000
#define NE 600000
#define D  128
#define C_SRC 0.5f   // (1 - alpha)
#define C_DST 0.5f   // alpha
#define SCAN_N (2 * NN)                 // 200000
#define NB ((SCAN_N + 255) / 256)       // 782

// deg[0..NN) = out-degree (row counts), deg[NN..2NN) = in-degree (col counts)
__global__ __launch_bounds__(256) void k_deg(const int* __restrict__ ei, int* __restrict__ deg) {
    int e = blockIdx.x * 256 + threadIdx.x;
    if (e < NE) {
        atomicAdd(&deg[ei[e]], 1);
        atomicAdd(&deg[NN + ei[NE + e]], 1);
    }
}

__global__ __launch_bounds__(256) void k_rinv(const int* __restrict__ deg, float* __restrict__ rinv) {
    int i = blockIdx.x * 256 + threadIdx.x;
    if (i < SCAN_N) {
        int d = deg[i];
        rinv[i] = d > 0 ? rsqrtf((float)d) : 0.f;
    }
}

// ---- hierarchical exclusive scan over deg[0..2NN) -> ptr ----
__global__ __launch_bounds__(256) void k_scan1(const int* __restrict__ deg,
                                               int* __restrict__ ptr, int* __restrict__ bsum) {
    __shared__ int s[256];
    int t = threadIdx.x;
    int i = blockIdx.x * 256 + t;
    int v = (i < SCAN_N) ? deg[i] : 0;
    s[t] = v;
    __syncthreads();
    #pragma unroll
    for (int off = 1; off < 256; off <<= 1) {
        int add = (t >= off) ? s[t - off] : 0;
        __syncthreads();
        s[t] += add;
        __syncthreads();
    }
    if (i < SCAN_N) ptr[i] = s[t] - v;   // exclusive
    if (t == 255) bsum[blockIdx.x] = s[255];
}

__global__ __launch_bounds__(1024) void k_scan2(int* __restrict__ bsum) {
    __shared__ int s[1024];
    int t = threadIdx.x;
    int v = (t < NB) ? bsum[t] : 0;
    s[t] = v;
    __syncthreads();
    #pragma unroll
    for (int off = 1; off < 1024; off <<= 1) {
        int add = (t >= off) ? s[t - off] : 0;
        __syncthreads();
        s[t] += add;
        __syncthreads();
    }
    if (t < NB) bsum[t] = s[t] - v;      // exclusive block offsets
}

__global__ __launch_bounds__(256) void k_scan3(int* __restrict__ ptr, const int* __restrict__ bsum) {
    int i = blockIdx.x * 256 + threadIdx.x;
    if (i < SCAN_N) ptr[i] += bsum[blockIdx.x];
}

// bucket-fill: idx[ptr[row]+k] = col  (region [0,E)), idx[ptr[NN+col]+k] = row (region [E,2E))
__global__ __launch_bounds__(256) void k_fill(const int* __restrict__ ei, const int* __restrict__ ptr,
                                              int* __restrict__ cur, int* __restrict__ idx) {
    int e = blockIdx.x * 256 + threadIdx.x;
    if (e < NE) {
        int row = ei[e], col = ei[NE + e];
        int p1 = ptr[row] + atomicAdd(&cur[row], 1);
        idx[p1] = col;
        int p2 = ptr[NN + col] + atomicAdd(&cur[NN + col], 1);
        idx[p2] = row;
    }
}

// y_s = x @ Ws^T, y_d = x @ Wd^T   (fp32, tiled 64x64, 4x4 per thread)
__global__ __launch_bounds__(256) void k_gemm(const float* __restrict__ x,
                                              const float* __restrict__ Ws,
                                              const float* __restrict__ Wd,
                                              float* __restrict__ ys,
                                              float* __restrict__ yd) {
    __shared__ float xs[64 * 128];
    __shared__ float wsh[128 * 64];
    const float* W = blockIdx.z ? Wd : Ws;
    float*       y = blockIdx.z ? yd : ys;
    const int n0 = blockIdx.x * 64;
    const int c0 = blockIdx.y * 64;
    const int tid = threadIdx.x;

    #pragma unroll
    for (int it = 0; it < 32; ++it) {
        int idx = it * 256 + tid;
        int r = idx >> 7, k = idx & 127;
        int n = n0 + r;
        xs[idx] = (n < NN) ? x[(size_t)n * D + k] : 0.f;
    }
    #pragma unroll
    for (int it = 0; it < 32; ++it) {
        int idx = it * 256 + tid;
        int jj = idx >> 7, k = idx & 127;
        wsh[k * 64 + (jj ^ ((k & 15) << 2))] = W[(size_t)(c0 + jj) * D + k];
    }
    __syncthreads();

    const int tx = tid & 15, ty = tid >> 4;
    const int cq = tx * 4, r0 = ty * 4;
    float acc[4][4] = {};
    #pragma unroll 4
    for (int k = 0; k < 128; ++k) {
        const float4 wv = *(const float4*)&wsh[k * 64 + (cq ^ ((k & 15) << 2))];
        #pragma unroll
        for (int r = 0; r < 4; ++r) {
            float xv = xs[(r0 + r) * 128 + k];
            acc[r][0] += xv * wv.x;
            acc[r][1] += xv * wv.y;
            acc[r][2] += xv * wv.z;
            acc[r][3] += xv * wv.w;
        }
    }
    #pragma unroll
    for (int r = 0; r < 4; ++r) {
        int n = n0 + r0 + r;
        if (n < NN) {
            float4 v = make_float4(acc[r][0], acc[r][1], acc[r][2], acc[r][3]);
            *(float4*)&y[(size_t)n * D + c0 + cq] = v;
        }
    }
}

// one 64-lane wave per node; float2 per lane over D=128; no f32 atomics anywhere
__global__ __launch_bounds__(256) void k_gather(const int* __restrict__ deg, const int* __restrict__ ptr,
                                                const int* __restrict__ idx, const float* __restrict__ rinv,
                                                const float* __restrict__ ys, const float* __restrict__ yd,
                                                const float* __restrict__ bs, const float* __restrict__ bd,
                                                float* __restrict__ out) {
    int wid = (blockIdx.x * 256 + threadIdx.x) >> 6;
    if (wid >= NN) return;
    int lane = threadIdx.x & 63;
    int j = lane << 1;
    int n = wid;
    float rn_out = rinv[n];
    float rn_in  = rinv[NN + n];

    float2 accS = make_float2(0.f, 0.f);
    float2 accD = make_float2(0.f, 0.f);

    int s1 = ptr[n], d1 = deg[n];
    for (int i = 0; i < d1; ++i) {
        int c = idx[s1 + i];
        float w = rn_out * rinv[NN + c];
        float2 v = *(const float2*)&ys[(size_t)c * D + j];
        accS.x += w * v.x;
        accS.y += w * v.y;
    }
    int s2 = ptr[NN + n], d2 = deg[NN + n];
    for (int i = 0; i < d2; ++i) {
        int r = idx[s2 + i];
        float w = rn_in * rinv[r];
        float2 v = *(const float2*)&yd[(size_t)r * D + j];
        accD.x += w * v.x;
        accD.y += w * v.y;
    }
    float2 o;
    o.x = C_SRC * accS.x + C_DST * accD.x + C_SRC * bs[j]     + C_DST * bd[j];
    o.y = C_SRC * accS.y + C_DST * accD.y + C_SRC * bs[j + 1] + C_DST * bd[j + 1];
    *(float2*)&out[(size_t)n * D + j] = o;
}

extern "C" void kernel_launch(void* const* d_in, const int* in_sizes, int n_in,
                              void* d_out, int out_size, void* d_ws, size_t ws_size,
                              hipStream_t stream) {
    const float* x  = (const float*)d_in[0];
    const int*   ei = (const int*)d_in[1];
    const float* Ws = (const float*)d_in[2];
    const float* bs = (const float*)d_in[3];
    const float* Wd = (const float*)d_in[4];
    const float* bd = (const float*)d_in[5];
    float* out = (float*)d_out;

    // workspace layout
    int*   deg  = (int*)d_ws;                 // 2N
    int*   cur  = deg + SCAN_N;               // 2N  (adjacent to deg: single memset)
    int*   ptr  = cur + SCAN_N;               // 2N
    int*   bsum = ptr + SCAN_N;               // 1024
    int*   idx  = bsum + 1024;                // 2E
    float* rinv = (float*)(idx + 2 * NE);     // 2N
    float* ys   = rinv + SCAN_N;              // NN*D
    float* yd   = ys + (size_t)NN * D;        // NN*D

    hipMemsetAsync(deg, 0, 2 * SCAN_N * sizeof(int), stream);   // deg + cur
    k_deg<<<(NE + 255) / 256, 256, 0, stream>>>(ei, deg);
    k_rinv<<<(SCAN_N + 255) / 256, 256, 0, stream>>>(deg, rinv);
    k_scan1<<<NB, 256, 0, stream>>>(deg, ptr, bsum);
    k_scan2<<<1, 1024, 0, stream>>>(bsum);
    k_scan3<<<NB, 256, 0, stream>>>(ptr, bsum);
    k_fill<<<(NE + 255) / 256, 256, 0, stream>>>(ei, ptr, cur, idx);

    dim3 gg((NN + 63) / 64, 2, 2);
    k_gemm<<<gg, 256, 0, stream>>>(x, Ws, Wd, ys, yd);
    k_gather<<<(NN * 64 + 255) / 256, 256, 0, stream>>>(deg, ptr, idx, rinv, ys, yd, bs, bd, out);
}

// Round 3
// 291.104 us; speedup vs baseline: 7.8328x; 1.6597x over previous
//
#include <hip/hip_runtime.h>

#define NN 100000
#define NE 600000
#define D  128
#define C_SRC 0.5f   // (1 - alpha)
#define C_DST 0.5f   // alpha
#define SCAN_N (2 * NN)                 // 200000
#define NB ((SCAN_N + 255) / 256)       // 782

typedef __attribute__((ext_vector_type(8))) short bf16x8;
typedef __attribute__((ext_vector_type(4))) float f32x4;

__device__ __forceinline__ ushort f2bf(float f) {
    union { float f; unsigned u; } v; v.f = f;
    unsigned r = v.u + 0x7fffu + ((v.u >> 16) & 1u);   // RNE
    return (ushort)(r >> 16);
}

__device__ __forceinline__ void gload_lds16(const void* g, void* l) {
    __builtin_amdgcn_global_load_lds((const __attribute__((address_space(1))) void*)g,
                                     (__attribute__((address_space(3))) void*)l, 16, 0, 0);
}

// deg[0..NN) = out-degree, deg[NN..2NN) = in-degree
__global__ __launch_bounds__(256) void k_deg(const int* __restrict__ ei, int* __restrict__ deg) {
    int e = blockIdx.x * 256 + threadIdx.x;
    if (e < NE) {
        atomicAdd(&deg[ei[e]], 1);
        atomicAdd(&deg[NN + ei[NE + e]], 1);
    }
}

__global__ __launch_bounds__(256) void k_rinv(const int* __restrict__ deg, float* __restrict__ rinv) {
    int i = blockIdx.x * 256 + threadIdx.x;
    if (i < SCAN_N) {
        int d = deg[i];
        rinv[i] = d > 0 ? rsqrtf((float)d) : 0.f;
    }
}

// ---- hierarchical exclusive scan over deg[0..2NN) -> ptr ----
__global__ __launch_bounds__(256) void k_scan1(const int* __restrict__ deg,
                                               int* __restrict__ ptr, int* __restrict__ bsum) {
    __shared__ int s[256];
    int t = threadIdx.x;
    int i = blockIdx.x * 256 + t;
    int v = (i < SCAN_N) ? deg[i] : 0;
    s[t] = v;
    __syncthreads();
    #pragma unroll
    for (int off = 1; off < 256; off <<= 1) {
        int add = (t >= off) ? s[t - off] : 0;
        __syncthreads();
        s[t] += add;
        __syncthreads();
    }
    if (i < SCAN_N) ptr[i] = s[t] - v;
    if (t == 255) bsum[blockIdx.x] = s[255];
}

__global__ __launch_bounds__(1024) void k_scan2(int* __restrict__ bsum) {
    __shared__ int s[1024];
    int t = threadIdx.x;
    int v = (t < NB) ? bsum[t] : 0;
    s[t] = v;
    __syncthreads();
    #pragma unroll
    for (int off = 1; off < 1024; off <<= 1) {
        int add = (t >= off) ? s[t - off] : 0;
        __syncthreads();
        s[t] += add;
        __syncthreads();
    }
    if (t < NB) bsum[t] = s[t] - v;
}

__global__ __launch_bounds__(256) void k_scan3(int* __restrict__ ptr, const int* __restrict__ bsum) {
    int i = blockIdx.x * 256 + threadIdx.x;
    if (i < SCAN_N) ptr[i] += bsum[blockIdx.x];
}

// fused convert: x -> xb (bf16), Ws|Wd -> wb (bf16, concatenated)
__global__ __launch_bounds__(256) void k_cvt(const float* __restrict__ x,
                                             const float* __restrict__ Ws,
                                             const float* __restrict__ Wd,
                                             ushort* __restrict__ xb, ushort* __restrict__ wb) {
    int t = blockIdx.x * 256 + threadIdx.x;
    int i4 = t * 4;
    if (i4 < NN * D) {
        float4 v = *(const float4*)&x[i4];
        ushort4 o = { f2bf(v.x), f2bf(v.y), f2bf(v.z), f2bf(v.w) };
        *(ushort4*)&xb[i4] = o;
    } else if (i4 < NN * D + 2 * D * D) {
        int t4 = i4 - NN * D;
        const float* W = (t4 < D * D) ? Ws : Wd;
        int o4 = (t4 < D * D) ? t4 : t4 - D * D;
        float4 v = *(const float4*)&W[o4];
        ushort4 o = { f2bf(v.x), f2bf(v.y), f2bf(v.z), f2bf(v.w) };
        *(ushort4*)&wb[t4] = o;
    }
}

// bucket-fill CSR with fused per-edge weight: entry = (neighbor, bits(w))
__global__ __launch_bounds__(256) void k_fill(const int* __restrict__ ei, const int* __restrict__ ptr,
                                              const float* __restrict__ rinv,
                                              int* __restrict__ cur, int2* __restrict__ idx2) {
    int e = blockIdx.x * 256 + threadIdx.x;
    if (e < NE) {
        int row = ei[e], col = ei[NE + e];
        float w = rinv[row] * rinv[NN + col];
        int wb = __float_as_int(w);
        int p1 = ptr[row] + atomicAdd(&cur[row], 1);
        idx2[p1] = make_int2(col, wb);
        int p2 = ptr[NN + col] + atomicAdd(&cur[NN + col], 1);
        idx2[p2] = make_int2(row, wb);
    }
}

// ys = x @ Ws^T, yd = x @ Wd^T  -- bf16 MFMA, 128x128 tile, swizzled LDS (T2 via rule-21)
__global__ __launch_bounds__(256) void k_gemm(const ushort* __restrict__ xb,
                                              const ushort* __restrict__ wb,
                                              ushort* __restrict__ ys, ushort* __restrict__ yd) {
    __shared__ ushort xs[128 * 128];   // 32 KiB, swizzled: LDS[row][cb] = g[row][cb ^ ((row&7)<<4)]
    __shared__ ushort wsh[128 * 128];  // 32 KiB
    const int n0 = blockIdx.x * 128;
    const ushort* W = wb + blockIdx.y * D * D;
    ushort* y = blockIdx.y ? yd : ys;
    const int tid = threadIdx.x, wv = tid >> 6, l = tid & 63;

    // stage: each wave-iteration covers 4 rows (1 KiB); source pre-swizzled
    #pragma unroll
    for (int i = 0; i < 8; ++i) {
        int grp = i * 4 + wv;                  // 0..31, wave-uniform
        int row = grp * 4 + (l >> 4);
        int cb  = (l & 15) << 4;               // byte offset in 256B row
        int sb  = cb ^ ((row & 7) << 4);
        int rg  = min(n0 + row, NN - 1);
        gload_lds16((const char*)xb + (size_t)rg * 256 + sb, (char*)xs + grp * 1024);
        gload_lds16((const char*)W + row * 256 + sb,         (char*)wsh + grp * 1024);
    }
    __syncthreads();

    const int wrow = wv * 32;
    const int lr = l & 15;
    const int lkb = (l >> 4) * 16;             // byte offset of lane's 8-elem k-run
    f32x4 acc[2][8] = {};
    #pragma unroll
    for (int ks = 0; ks < 4; ++ks) {
        int kb = ks * 64 + lkb;                // byte offset within 256B row
        bf16x8 a[2], b[8];
        #pragma unroll
        for (int m = 0; m < 2; ++m) {
            int row = wrow + m * 16 + lr;
            a[m] = *(const bf16x8*)((const char*)xs + row * 256 + (kb ^ ((row & 7) << 4)));
        }
        #pragma unroll
        for (int n = 0; n < 8; ++n) {
            int row = n * 16 + lr;             // W row == output col
            b[n] = *(const bf16x8*)((const char*)wsh + row * 256 + (kb ^ ((row & 7) << 4)));
        }
        #pragma unroll
        for (int m = 0; m < 2; ++m)
            #pragma unroll
            for (int n = 0; n < 8; ++n)
                acc[m][n] = __builtin_amdgcn_mfma_f32_16x16x32_bf16(a[m], b[n], acc[m][n], 0, 0, 0);
    }

    // C/D layout: col = l&15, row = (l>>4)*4 + reg
    #pragma unroll
    for (int m = 0; m < 2; ++m) {
        int rbase = n0 + wrow + m * 16 + (l >> 4) * 4;
        #pragma unroll
        for (int r = 0; r < 4; ++r) {
            int row = rbase + r;
            if (row < NN) {
                #pragma unroll
                for (int n = 0; n < 8; ++n)
                    y[(size_t)row * D + n * 16 + (l & 15)] = f2bf(acc[m][n][r]);
            }
        }
    }
}

// one 64-lane wave per node; 2 bf16 per lane; no f32 atomics
__global__ __launch_bounds__(256) void k_gather(const int* __restrict__ deg, const int* __restrict__ ptr,
                                                const int2* __restrict__ idx2,
                                                const ushort* __restrict__ ys, const ushort* __restrict__ yd,
                                                const float* __restrict__ bs, const float* __restrict__ bd,
                                                float* __restrict__ out) {
    int wid = (blockIdx.x * 256 + threadIdx.x) >> 6;
    if (wid >= NN) return;
    int lane = threadIdx.x & 63;
    int j = lane << 1;
    int n = wid;

    float2 accS = make_float2(0.f, 0.f);
    float2 accD = make_float2(0.f, 0.f);

    int s1 = ptr[n], d1 = deg[n];
    for (int i = 0; i < d1; ++i) {
        int2 e = idx2[s1 + i];                          // wave-uniform 8B
        float w = __int_as_float(e.y);
        unsigned u = *(const unsigned*)&ys[(size_t)e.x * D + j];
        accS.x += w * __uint_as_float(u << 16);
        accS.y += w * __uint_as_float(u & 0xffff0000u);
    }
    int s2 = ptr[NN + n], d2 = deg[NN + n];
    for (int i = 0; i < d2; ++i) {
        int2 e = idx2[s2 + i];
        float w = __int_as_float(e.y);
        unsigned u = *(const unsigned*)&yd[(size_t)e.x * D + j];
        accD.x += w * __uint_as_float(u << 16);
        accD.y += w * __uint_as_float(u & 0xffff0000u);
    }
    float2 o;
    o.x = C_SRC * accS.x + C_DST * accD.x + C_SRC * bs[j]     + C_DST * bd[j];
    o.y = C_SRC * accS.y + C_DST * accD.y + C_SRC * bs[j + 1] + C_DST * bd[j + 1];
    *(float2*)&out[(size_t)n * D + j] = o;
}

extern "C" void kernel_launch(void* const* d_in, const int* in_sizes, int n_in,
                              void* d_out, int out_size, void* d_ws, size_t ws_size,
                              hipStream_t stream) {
    const float* x  = (const float*)d_in[0];
    const int*   ei = (const int*)d_in[1];
    const float* Ws = (const float*)d_in[2];
    const float* bs = (const float*)d_in[3];
    const float* Wd = (const float*)d_in[4];
    const float* bd = (const float*)d_in[5];
    float* out = (float*)d_out;

    // workspace layout
    int*    deg  = (int*)d_ws;                  // 2N
    int*    cur  = deg + SCAN_N;                // 2N (adjacent: single memset)
    int*    ptr  = cur + SCAN_N;                // 2N
    int*    bsum = ptr + SCAN_N;                // 1024
    int2*   idx2 = (int2*)(bsum + 1024);        // 2E int2
    float*  rinv = (float*)(idx2 + 2 * NE);     // 2N
    ushort* xb   = (ushort*)(rinv + SCAN_N);    // NN*D bf16
    ushort* wb   = xb + (size_t)NN * D;         // 2*D*D bf16
    ushort* ysb  = wb + 2 * D * D;              // NN*D bf16
    ushort* ydb  = ysb + (size_t)NN * D;        // NN*D bf16

    hipMemsetAsync(deg, 0, 2 * SCAN_N * sizeof(int), stream);   // deg + cur
    k_deg<<<(NE + 255) / 256, 256, 0, stream>>>(ei, deg);
    k_rinv<<<(SCAN_N + 255) / 256, 256, 0, stream>>>(deg, rinv);
    k_scan1<<<NB, 256, 0, stream>>>(deg, ptr, bsum);
    k_scan2<<<1, 1024, 0, stream>>>(bsum);
    k_scan3<<<NB, 256, 0, stream>>>(ptr, bsum);
    k_fill<<<(NE + 255) / 256, 256, 0, stream>>>(ei, ptr, rinv, cur, idx2);

    int cvt_n = NN * D + 2 * D * D;
    k_cvt<<<(cvt_n / 4 + 255) / 256, 256, 0, stream>>>(x, Ws, Wd, xb, wb);
    dim3 gg((NN + 127) / 128, 2);
    k_gemm<<<gg, 256, 0, stream>>>(xb, wb, ysb, ydb);
    k_gather<<<(NN * 64 + 255) / 256, 256, 0, stream>>>(deg, ptr, idx2, ysb, ydb, bs, bd, out);
}

// Round 5
// 220.755 us; speedup vs baseline: 10.3289x; 1.3187x over previous
//
#include <hip/hip_runtime.h>

#define NN 100000
#define NE 600000
#define D  128
#define C_SRC 0.5f   // (1 - alpha)
#define C_DST 0.5f   // alpha
#define SCAN_N (2 * NN)                 // 200000
#define NB ((SCAN_N + 255) / 256)       // 782

typedef __attribute__((ext_vector_type(8))) short bf16x8;
typedef __attribute__((ext_vector_type(4))) float f32x4;

__device__ __forceinline__ ushort f2bf(float f) {
    union { float f; unsigned u; } v; v.f = f;
    unsigned r = v.u + 0x7fffu + ((v.u >> 16) & 1u);   // RNE
    return (ushort)(r >> 16);
}
__device__ __forceinline__ float bflo(unsigned u) { return __uint_as_float(u << 16); }
__device__ __forceinline__ float bfhi(unsigned u) { return __uint_as_float(u & 0xffff0000u); }

__device__ __forceinline__ void gload_lds16(const void* g, void* l) {
    __builtin_amdgcn_global_load_lds((const __attribute__((address_space(1))) void*)g,
                                     (__attribute__((address_space(3))) void*)l, 16, 0, 0);
}

// deg[0..NN) = out-degree, deg[NN..2NN) = in-degree
__global__ __launch_bounds__(256) void k_deg(const int* __restrict__ ei, int* __restrict__ deg) {
    int e = blockIdx.x * 256 + threadIdx.x;
    if (e < NE) {
        atomicAdd(&deg[ei[e]], 1);
        atomicAdd(&deg[NN + ei[NE + e]], 1);
    }
}

__global__ __launch_bounds__(256) void k_rinv(const int* __restrict__ deg, float* __restrict__ rinv) {
    int i = blockIdx.x * 256 + threadIdx.x;
    if (i < SCAN_N) {
        int d = deg[i];
        rinv[i] = d > 0 ? rsqrtf((float)d) : 0.f;
    }
}

// ---- hierarchical exclusive scan over deg[0..2NN) -> ptr ----
__global__ __launch_bounds__(256) void k_scan1(const int* __restrict__ deg,
                                               int* __restrict__ ptr, int* __restrict__ bsum) {
    __shared__ int s[256];
    int t = threadIdx.x;
    int i = blockIdx.x * 256 + t;
    int v = (i < SCAN_N) ? deg[i] : 0;
    s[t] = v;
    __syncthreads();
    #pragma unroll
    for (int off = 1; off < 256; off <<= 1) {
        int add = (t >= off) ? s[t - off] : 0;
        __syncthreads();
        s[t] += add;
        __syncthreads();
    }
    if (i < SCAN_N) ptr[i] = s[t] - v;
    if (t == 255) bsum[blockIdx.x] = s[255];
}

__global__ __launch_bounds__(1024) void k_scan2(int* __restrict__ bsum) {
    __shared__ int s[1024];
    int t = threadIdx.x;
    int v = (t < NB) ? bsum[t] : 0;
    s[t] = v;
    __syncthreads();
    #pragma unroll
    for (int off = 1; off < 1024; off <<= 1) {
        int add = (t >= off) ? s[t - off] : 0;
        __syncthreads();
        s[t] += add;
        __syncthreads();
    }
    if (t < NB) bsum[t] = s[t] - v;
}

__global__ __launch_bounds__(256) void k_scan3(int* __restrict__ ptr, const int* __restrict__ bsum) {
    int i = blockIdx.x * 256 + threadIdx.x;
    if (i < SCAN_N) ptr[i] += bsum[blockIdx.x];
}

// fused convert: x -> xb (bf16), Ws|Wd -> wb (bf16, concatenated)
__global__ __launch_bounds__(256) void k_cvt(const float* __restrict__ x,
                                             const float* __restrict__ Ws,
                                             const float* __restrict__ Wd,
                                             ushort* __restrict__ xb, ushort* __restrict__ wb) {
    int t = blockIdx.x * 256 + threadIdx.x;
    int i4 = t * 4;
    if (i4 < NN * D) {
        float4 v = *(const float4*)&x[i4];
        ushort4 o = { f2bf(v.x), f2bf(v.y), f2bf(v.z), f2bf(v.w) };
        *(ushort4*)&xb[i4] = o;
    } else if (i4 < NN * D + 2 * D * D) {
        int t4 = i4 - NN * D;
        const float* W = (t4 < D * D) ? Ws : Wd;
        int o4 = (t4 < D * D) ? t4 : t4 - D * D;
        float4 v = *(const float4*)&W[o4];
        ushort4 o = { f2bf(v.x), f2bf(v.y), f2bf(v.z), f2bf(v.w) };
        *(ushort4*)&wb[t4] = o;
    }
}

// bucket-fill CSR with fused per-edge weight: entry = (neighbor, bits(w))
__global__ __launch_bounds__(256) void k_fill(const int* __restrict__ ei, const int* __restrict__ ptr,
                                              const float* __restrict__ rinv,
                                              int* __restrict__ cur, int2* __restrict__ idx2) {
    int e = blockIdx.x * 256 + threadIdx.x;
    if (e < NE) {
        int row = ei[e], col = ei[NE + e];
        float w = rinv[row] * rinv[NN + col];
        int wb = __float_as_int(w);
        int p1 = ptr[row] + atomicAdd(&cur[row], 1);
        idx2[p1] = make_int2(col, wb);
        int p2 = ptr[NN + col] + atomicAdd(&cur[NN + col], 1);
        idx2[p2] = make_int2(row, wb);
    }
}

// ys = x @ Ws^T, yd = x @ Wd^T  -- bf16 MFMA, 128x128 tile, swizzled LDS (T2 via rule-21)
__global__ __launch_bounds__(256) void k_gemm(const ushort* __restrict__ xb,
                                              const ushort* __restrict__ wb,
                                              ushort* __restrict__ ys, ushort* __restrict__ yd) {
    __shared__ ushort xs[128 * 128];   // 32 KiB, swizzled: LDS[row][cb] = g[row][cb ^ ((row&7)<<4)]
    __shared__ ushort wsh[128 * 128];  // 32 KiB
    const int n0 = blockIdx.x * 128;
    const ushort* W = wb + blockIdx.y * D * D;
    ushort* y = blockIdx.y ? yd : ys;
    const int tid = threadIdx.x, wv = tid >> 6, l = tid & 63;

    // stage: each wave-iteration covers 4 rows (1 KiB); source pre-swizzled
    #pragma unroll
    for (int i = 0; i < 8; ++i) {
        int grp = i * 4 + wv;                  // 0..31, wave-uniform
        int row = grp * 4 + (l >> 4);
        int cb  = (l & 15) << 4;               // byte offset in 256B row
        int sb  = cb ^ ((row & 7) << 4);
        int rg  = min(n0 + row, NN - 1);
        gload_lds16((const char*)xb + (size_t)rg * 256 + sb, (char*)xs + grp * 1024);
        gload_lds16((const char*)W + row * 256 + sb,         (char*)wsh + grp * 1024);
    }
    __syncthreads();

    const int wrow = wv * 32;
    const int lr = l & 15;
    const int lkb = (l >> 4) * 16;             // byte offset of lane's 8-elem k-run
    f32x4 acc[2][8] = {};
    #pragma unroll
    for (int ks = 0; ks < 4; ++ks) {
        int kb = ks * 64 + lkb;                // byte offset within 256B row
        bf16x8 a[2], b[8];
        #pragma unroll
        for (int m = 0; m < 2; ++m) {
            int row = wrow + m * 16 + lr;
            a[m] = *(const bf16x8*)((const char*)xs + row * 256 + (kb ^ ((row & 7) << 4)));
        }
        #pragma unroll
        for (int n = 0; n < 8; ++n) {
            int row = n * 16 + lr;             // W row == output col
            b[n] = *(const bf16x8*)((const char*)wsh + row * 256 + (kb ^ ((row & 7) << 4)));
        }
        #pragma unroll
        for (int m = 0; m < 2; ++m)
            #pragma unroll
            for (int n = 0; n < 8; ++n)
                acc[m][n] = __builtin_amdgcn_mfma_f32_16x16x32_bf16(a[m], b[n], acc[m][n], 0, 0, 0);
    }

    // C/D layout: col = l&15, row = (l>>4)*4 + reg
    #pragma unroll
    for (int m = 0; m < 2; ++m) {
        int rbase = n0 + wrow + m * 16 + (l >> 4) * 4;
        #pragma unroll
        for (int r = 0; r < 4; ++r) {
            int row = rbase + r;
            if (row < NN) {
                #pragma unroll
                for (int n = 0; n < 8; ++n)
                    y[(size_t)row * D + n * 16 + (l & 15)] = f2bf(acc[m][n][r]);
            }
        }
    }
}

// half-wave split gather: lanes 0-31 = S direction (ys), 32-63 = D direction (yd).
// Main loop: 4 edges/iter, fully in-bounds loads; scalar peel for tail (<=3).
__global__ __launch_bounds__(256) void k_gather(const int* __restrict__ deg, const int* __restrict__ ptr,
                                                const int2* __restrict__ idx2,
                                                const ushort* __restrict__ ys, const ushort* __restrict__ yd,
                                                const float* __restrict__ bs, const float* __restrict__ bd,
                                                float* __restrict__ out) {
    int wid = (blockIdx.x * 256 + threadIdx.x) >> 6;
    if (wid >= NN) return;
    int lane = threadIdx.x & 63;
    int half = lane >> 5;
    int l5 = lane & 31;
    int base = wid + half * NN;
    int s = ptr[base];
    int d = deg[base];
    const ushort* y = half ? yd : ys;
    float coef = half ? C_DST : C_SRC;
    int j = l5 * 4;

    float4 acc = make_float4(0.f, 0.f, 0.f, 0.f);
    int i = 0;
    for (; i + 4 <= d; i += 4) {
        int2 e0 = idx2[s + i];
        int2 e1 = idx2[s + i + 1];
        int2 e2 = idx2[s + i + 2];
        int2 e3 = idx2[s + i + 3];
        uint2 u0 = *(const uint2*)(y + ((size_t)e0.x << 7) + j);
        uint2 u1 = *(const uint2*)(y + ((size_t)e1.x << 7) + j);
        uint2 u2 = *(const uint2*)(y + ((size_t)e2.x << 7) + j);
        uint2 u3 = *(const uint2*)(y + ((size_t)e3.x << 7) + j);
        float w0 = __int_as_float(e0.y);
        float w1 = __int_as_float(e1.y);
        float w2 = __int_as_float(e2.y);
        float w3 = __int_as_float(e3.y);
        acc.x += w0 * bflo(u0.x) + w1 * bflo(u1.x) + w2 * bflo(u2.x) + w3 * bflo(u3.x);
        acc.y += w0 * bfhi(u0.x) + w1 * bfhi(u1.x) + w2 * bfhi(u2.x) + w3 * bfhi(u3.x);
        acc.z += w0 * bflo(u0.y) + w1 * bflo(u1.y) + w2 * bflo(u2.y) + w3 * bflo(u3.y);
        acc.w += w0 * bfhi(u0.y) + w1 * bfhi(u1.y) + w2 * bfhi(u2.y) + w3 * bfhi(u3.y);
    }
    for (; i < d; ++i) {
        int2 e = idx2[s + i];
        uint2 u = *(const uint2*)(y + ((size_t)e.x << 7) + j);
        float w = __int_as_float(e.y);
        acc.x += w * bflo(u.x);
        acc.y += w * bfhi(u.x);
        acc.z += w * bflo(u.y);
        acc.w += w * bfhi(u.y);
    }
    const float* bb = half ? bd : bs;
    float4 bv = *(const float4*)&bb[j];
    acc.x = coef * (acc.x + bv.x);
    acc.y = coef * (acc.y + bv.y);
    acc.z = coef * (acc.z + bv.z);
    acc.w = coef * (acc.w + bv.w);
    acc.x += __shfl_xor(acc.x, 32);
    acc.y += __shfl_xor(acc.y, 32);
    acc.z += __shfl_xor(acc.z, 32);
    acc.w += __shfl_xor(acc.w, 32);
    if (!half) *(float4*)&out[(size_t)wid * D + j] = acc;
}

extern "C" void kernel_launch(void* const* d_in, const int* in_sizes, int n_in,
                              void* d_out, int out_size, void* d_ws, size_t ws_size,
                              hipStream_t stream) {
    const float* x  = (const float*)d_in[0];
    const int*   ei = (const int*)d_in[1];
    const float* Ws = (const float*)d_in[2];
    const float* bs = (const float*)d_in[3];
    const float* Wd = (const float*)d_in[4];
    const float* bd = (const float*)d_in[5];
    float* out = (float*)d_out;

    // workspace layout (round-3 proven)
    int*    deg  = (int*)d_ws;                  // 2N
    int*    cur  = deg + SCAN_N;                // 2N (adjacent: single memset)
    int*    ptr  = cur + SCAN_N;                // 2N
    int*    bsum = ptr + SCAN_N;                // 1024
    int2*   idx2 = (int2*)(bsum + 1024);        // 2E int2
    float*  rinv = (float*)(idx2 + 2 * NE);     // 2N
    ushort* xb   = (ushort*)(rinv + SCAN_N);    // NN*D bf16
    ushort* wb   = xb + (size_t)NN * D;         // 2*D*D bf16
    ushort* ysb  = wb + 2 * D * D;              // NN*D bf16
    ushort* ydb  = ysb + (size_t)NN * D;        // NN*D bf16

    hipMemsetAsync(deg, 0, 2 * SCAN_N * sizeof(int), stream);   // deg + cur
    k_deg<<<(NE + 255) / 256, 256, 0, stream>>>(ei, deg);
    k_rinv<<<(SCAN_N + 255) / 256, 256, 0, stream>>>(deg, rinv);
    k_scan1<<<NB, 256, 0, stream>>>(deg, ptr, bsum);
    k_scan2<<<1, 1024, 0, stream>>>(bsum);
    k_scan3<<<NB, 256, 0, stream>>>(ptr, bsum);
    k_fill<<<(NE + 255) / 256, 256, 0, stream>>>(ei, ptr, rinv, cur, idx2);

    int cvt_n = NN * D + 2 * D * D;
    k_cvt<<<(cvt_n / 4 + 255) / 256, 256, 0, stream>>>(x, Ws, Wd, xb, wb);
    dim3 gg((NN + 127) / 128, 2);
    k_gemm<<<gg, 256, 0, stream>>>(xb, wb, ysb, ydb);
    k_gather<<<(NN * 64 + 255) / 256, 256, 0, stream>>>(deg, ptr, idx2, ysb, ydb, bs, bd, out);
}

// Round 6
// 216.872 us; speedup vs baseline: 10.5138x; 1.0179x over previous
//
#include <hip/hip_runtime.h>

#define NN 100000
#define NE 600000
#define D  128
#define C_SRC 0.5f   // (1 - alpha)
#define C_DST 0.5f   // alpha
#define SCAN_N (2 * NN)                 // 200000
#define NB ((SCAN_N + 255) / 256)       // 782

typedef __attribute__((ext_vector_type(8))) short bf16x8;
typedef __attribute__((ext_vector_type(4))) float f32x4;

__device__ __forceinline__ ushort f2bf(float f) {
    union { float f; unsigned u; } v; v.f = f;
    unsigned r = v.u + 0x7fffu + ((v.u >> 16) & 1u);   // RNE
    return (ushort)(r >> 16);
}
__device__ __forceinline__ float bflo(unsigned u) { return __uint_as_float(u << 16); }
__device__ __forceinline__ float bfhi(unsigned u) { return __uint_as_float(u & 0xffff0000u); }

// deg[0..NN) = out-degree, deg[NN..2NN) = in-degree
__global__ __launch_bounds__(256) void k_deg(const int* __restrict__ ei, int* __restrict__ deg) {
    int e = blockIdx.x * 256 + threadIdx.x;
    if (e < NE) {
        atomicAdd(&deg[ei[e]], 1);
        atomicAdd(&deg[NN + ei[NE + e]], 1);
    }
}

// ---- hierarchical exclusive scan over deg[0..2NN) -> ptr; also emits rinv ----
__global__ __launch_bounds__(256) void k_scan1(const int* __restrict__ deg,
                                               int* __restrict__ ptr, int* __restrict__ bsum,
                                               float* __restrict__ rinv) {
    __shared__ int s[256];
    int t = threadIdx.x;
    int i = blockIdx.x * 256 + t;
    int v = (i < SCAN_N) ? deg[i] : 0;
    s[t] = v;
    __syncthreads();
    #pragma unroll
    for (int off = 1; off < 256; off <<= 1) {
        int add = (t >= off) ? s[t - off] : 0;
        __syncthreads();
        s[t] += add;
        __syncthreads();
    }
    if (i < SCAN_N) {
        ptr[i] = s[t] - v;
        rinv[i] = v > 0 ? rsqrtf((float)v) : 0.f;
    }
    if (t == 255) bsum[blockIdx.x] = s[255];
}

__global__ __launch_bounds__(1024) void k_scan2(int* __restrict__ bsum) {
    __shared__ int s[1024];
    int t = threadIdx.x;
    int v = (t < NB) ? bsum[t] : 0;
    s[t] = v;
    __syncthreads();
    #pragma unroll
    for (int off = 1; off < 1024; off <<= 1) {
        int add = (t >= off) ? s[t - off] : 0;
        __syncthreads();
        s[t] += add;
        __syncthreads();
    }
    if (t < NB) bsum[t] = s[t] - v;
}

__global__ __launch_bounds__(256) void k_scan3(int* __restrict__ ptr, const int* __restrict__ bsum) {
    int i = blockIdx.x * 256 + threadIdx.x;
    if (i < SCAN_N) ptr[i] += bsum[blockIdx.x];
}

// bucket-fill CSR with fused per-edge weight: entry = (neighbor, bits(w))
__global__ __launch_bounds__(256) void k_fill(const int* __restrict__ ei, const int* __restrict__ ptr,
                                              const float* __restrict__ rinv,
                                              int* __restrict__ cur, int2* __restrict__ idx2) {
    int e = blockIdx.x * 256 + threadIdx.x;
    if (e < NE) {
        int row = ei[e], col = ei[NE + e];
        float w = rinv[row] * rinv[NN + col];
        int wb = __float_as_int(w);
        int p1 = ptr[row] + atomicAdd(&cur[row], 1);
        idx2[p1] = make_int2(col, wb);
        int p2 = ptr[NN + col] + atomicAdd(&cur[NN + col], 1);
        idx2[p2] = make_int2(row, wb);
    }
}

// ys = x @ Ws^T, yd = x @ Wd^T  -- fused fp32->bf16 convert + both GEMMs per block.
// LDS swizzle: lds_byte(row, cb) = row*256 + (cb ^ ((row&7)<<4))   (write & read sides match)
__global__ __launch_bounds__(512) void k_gemm(const float* __restrict__ x,
                                              const float* __restrict__ Ws,
                                              const float* __restrict__ Wd,
                                              ushort* __restrict__ ys, ushort* __restrict__ yd) {
    __shared__ ushort xs[128 * 128];       // 32 KiB
    __shared__ ushort wsh[2 * 128 * 128];  // 64 KiB
    const int n0 = blockIdx.x * 128;
    const int tid = threadIdx.x;

    // stage x tile (convert in-reg)
    #pragma unroll
    for (int i = 0; i < 4; ++i) {
        int c = i * 512 + tid;                 // 0..2047 chunks of 8 cols
        int row = c >> 4, colb = (c & 15) * 8;
        int rg = min(n0 + row, NN - 1);
        const float* px = x + (size_t)rg * D + colb;
        float4 v0 = *(const float4*)px;
        float4 v1 = *(const float4*)(px + 4);
        bf16x8 o = { (short)f2bf(v0.x), (short)f2bf(v0.y), (short)f2bf(v0.z), (short)f2bf(v0.w),
                     (short)f2bf(v1.x), (short)f2bf(v1.y), (short)f2bf(v1.z), (short)f2bf(v1.w) };
        *(bf16x8*)((char*)xs + row * 256 + (((c & 15) * 16) ^ ((row & 7) << 4))) = o;
    }
    // stage both W (convert in-reg)
    #pragma unroll
    for (int i = 0; i < 8; ++i) {
        int c = i * 512 + tid;                 // 0..4095
        int m = c >> 11, cc = c & 2047;
        int row = cc >> 4, colb = (cc & 15) * 8;
        const float* pw = (m ? Wd : Ws) + row * D + colb;
        float4 v0 = *(const float4*)pw;
        float4 v1 = *(const float4*)(pw + 4);
        bf16x8 o = { (short)f2bf(v0.x), (short)f2bf(v0.y), (short)f2bf(v0.z), (short)f2bf(v0.w),
                     (short)f2bf(v1.x), (short)f2bf(v1.y), (short)f2bf(v1.z), (short)f2bf(v1.w) };
        *(bf16x8*)((char*)wsh + m * 32768 + row * 256 + (((cc & 15) * 16) ^ ((row & 7) << 4))) = o;
    }
    __syncthreads();

    const int wv = tid >> 6, l = tid & 63;
    const int wrow = wv * 16;                  // 8 waves x 16 rows
    const int lr = l & 15;
    const int lkb = (l >> 4) * 16;
    #pragma unroll
    for (int w = 0; w < 2; ++w) {
        f32x4 acc[8] = {};
        #pragma unroll
        for (int ks = 0; ks < 4; ++ks) {
            int kb = ks * 64 + lkb;
            int arow = wrow + lr;
            bf16x8 a = *(const bf16x8*)((const char*)xs + arow * 256 + (kb ^ ((arow & 7) << 4)));
            #pragma unroll
            for (int n = 0; n < 8; ++n) {
                int brow = n * 16 + lr;
                bf16x8 b = *(const bf16x8*)((const char*)wsh + w * 32768 + brow * 256 + (kb ^ ((brow & 7) << 4)));
                acc[n] = __builtin_amdgcn_mfma_f32_16x16x32_bf16(a, b, acc[n], 0, 0, 0);
            }
        }
        ushort* y = w ? yd : ys;
        int rbase = n0 + wrow + (l >> 4) * 4;
        #pragma unroll
        for (int r = 0; r < 4; ++r) {
            int row = rbase + r;
            if (row < NN) {
                #pragma unroll
                for (int n = 0; n < 8; ++n)
                    y[(size_t)row * D + n * 16 + lr] = f2bf(acc[n][r]);
            }
        }
    }
}

// half-wave split gather (round-5 proven, byte-identical): lanes 0-31 = ys, 32-63 = yd.
__global__ __launch_bounds__(256) void k_gather(const int* __restrict__ deg, const int* __restrict__ ptr,
                                                const int2* __restrict__ idx2,
                                                const ushort* __restrict__ ys, const ushort* __restrict__ yd,
                                                const float* __restrict__ bs, const float* __restrict__ bd,
                                                float* __restrict__ out) {
    int wid = (blockIdx.x * 256 + threadIdx.x) >> 6;
    if (wid >= NN) return;
    int lane = threadIdx.x & 63;
    int half = lane >> 5;
    int l5 = lane & 31;
    int base = wid + half * NN;
    int s = ptr[base];
    int d = deg[base];
    const ushort* y = half ? yd : ys;
    float coef = half ? C_DST : C_SRC;
    int j = l5 * 4;

    float4 acc = make_float4(0.f, 0.f, 0.f, 0.f);
    int i = 0;
    for (; i + 4 <= d; i += 4) {
        int2 e0 = idx2[s + i];
        int2 e1 = idx2[s + i + 1];
        int2 e2 = idx2[s + i + 2];
        int2 e3 = idx2[s + i + 3];
        uint2 u0 = *(const uint2*)(y + ((size_t)e0.x << 7) + j);
        uint2 u1 = *(const uint2*)(y + ((size_t)e1.x << 7) + j);
        uint2 u2 = *(const uint2*)(y + ((size_t)e2.x << 7) + j);
        uint2 u3 = *(const uint2*)(y + ((size_t)e3.x << 7) + j);
        float w0 = __int_as_float(e0.y);
        float w1 = __int_as_float(e1.y);
        float w2 = __int_as_float(e2.y);
        float w3 = __int_as_float(e3.y);
        acc.x += w0 * bflo(u0.x) + w1 * bflo(u1.x) + w2 * bflo(u2.x) + w3 * bflo(u3.x);
        acc.y += w0 * bfhi(u0.x) + w1 * bfhi(u1.x) + w2 * bfhi(u2.x) + w3 * bfhi(u3.x);
        acc.z += w0 * bflo(u0.y) + w1 * bflo(u1.y) + w2 * bflo(u2.y) + w3 * bflo(u3.y);
        acc.w += w0 * bfhi(u0.y) + w1 * bfhi(u1.y) + w2 * bfhi(u2.y) + w3 * bfhi(u3.y);
    }
    for (; i < d; ++i) {
        int2 e = idx2[s + i];
        uint2 u = *(const uint2*)(y + ((size_t)e.x << 7) + j);
        float w = __int_as_float(e.y);
        acc.x += w * bflo(u.x);
        acc.y += w * bfhi(u.x);
        acc.z += w * bflo(u.y);
        acc.w += w * bfhi(u.y);
    }
    const float* bb = half ? bd : bs;
    float4 bv = *(const float4*)&bb[j];
    acc.x = coef * (acc.x + bv.x);
    acc.y = coef * (acc.y + bv.y);
    acc.z = coef * (acc.z + bv.z);
    acc.w = coef * (acc.w + bv.w);
    acc.x += __shfl_xor(acc.x, 32);
    acc.y += __shfl_xor(acc.y, 32);
    acc.z += __shfl_xor(acc.z, 32);
    acc.w += __shfl_xor(acc.w, 32);
    if (!half) *(float4*)&out[(size_t)wid * D + j] = acc;
}

extern "C" void kernel_launch(void* const* d_in, const int* in_sizes, int n_in,
                              void* d_out, int out_size, void* d_ws, size_t ws_size,
                              hipStream_t stream) {
    const float* x  = (const float*)d_in[0];
    const int*   ei = (const int*)d_in[1];
    const float* Ws = (const float*)d_in[2];
    const float* bs = (const float*)d_in[3];
    const float* Wd = (const float*)d_in[4];
    const float* bd = (const float*)d_in[5];
    float* out = (float*)d_out;

    // workspace layout
    int*    deg  = (int*)d_ws;                  // 2N
    int*    cur  = deg + SCAN_N;                // 2N (adjacent: single memset)
    int*    ptr  = cur + SCAN_N;                // 2N
    int*    bsum = ptr + SCAN_N;                // 1024
    int2*   idx2 = (int2*)(bsum + 1024);        // 2E int2
    float*  rinv = (float*)(idx2 + 2 * NE);     // 2N
    ushort* ysb  = (ushort*)(rinv + SCAN_N);    // NN*D bf16
    ushort* ydb  = ysb + (size_t)NN * D;        // NN*D bf16

    hipMemsetAsync(deg, 0, 2 * SCAN_N * sizeof(int), stream);   // deg + cur
    k_deg<<<(NE + 255) / 256, 256, 0, stream>>>(ei, deg);
    k_scan1<<<NB, 256, 0, stream>>>(deg, ptr, bsum, rinv);
    k_scan2<<<1, 1024, 0, stream>>>(bsum);
    k_scan3<<<NB, 256, 0, stream>>>(ptr, bsum);
    k_fill<<<(NE + 255) / 256, 256, 0, stream>>>(ei, ptr, rinv, cur, idx2);

    k_gemm<<<(NN + 127) / 128, 512, 0, stream>>>(x, Ws, Wd, ysb, ydb);
    k_gather<<<(NN * 64 + 255) / 256, 256, 0, stream>>>(deg, ptr, idx2, ysb, ydb, bs, bd, out);
}

// Round 7
// 179.530 us; speedup vs baseline: 12.7007x; 1.2080x over previous
//
#include <hip/hip_runtime.h>

#define NN 100000
#define NE 600000
#define D  128
#define C_SRC 0.5f   // (1 - alpha)
#define C_DST 0.5f   // alpha
#define SCAN_N (2 * NN)                 // 200000
#define NB ((SCAN_N + 255) / 256)       // 782
#define GEMM_BLKS (2 * ((NN + 127) / 128))   // 1564: 782 tiles x 2 weights
#define DEG_BLKS  ((NE + 511) / 512)         // 1172

typedef __attribute__((ext_vector_type(8))) short bf16x8;
typedef __attribute__((ext_vector_type(4))) float f32x4;

__device__ __forceinline__ ushort f2bf(float f) {
    union { float f; unsigned u; } v; v.f = f;
    unsigned r = v.u + 0x7fffu + ((v.u >> 16) & 1u);   // RNE
    return (ushort)(r >> 16);
}
__device__ __forceinline__ float bflo(unsigned u) { return __uint_as_float(u << 16); }
__device__ __forceinline__ float bfhi(unsigned u) { return __uint_as_float(u & 0xffff0000u); }

// Fused: blocks [0, GEMM_BLKS) = GEMM (ys/yd = x @ W^T, one W per block, 64 KiB LDS);
//        blocks [GEMM_BLKS, +DEG_BLKS) = degree count + rank capture.
// Independent work on different pipes -> co-scheduled on CUs.
__global__ __launch_bounds__(512) void k_main(const float* __restrict__ x,
                                              const float* __restrict__ Ws,
                                              const float* __restrict__ Wd,
                                              const int* __restrict__ ei,
                                              int* __restrict__ deg, ushort2* __restrict__ rank,
                                              ushort* __restrict__ ys, ushort* __restrict__ yd) {
    __shared__ ushort xs[128 * 128];   // 32 KiB
    __shared__ ushort wsh[128 * 128];  // 32 KiB
    const int bx = blockIdx.x;
    const int tid = threadIdx.x;

    if (bx >= GEMM_BLKS) {             // ---- deg partition ----
        int e = (bx - GEMM_BLKS) * 512 + tid;
        if (e < NE) {
            int row = ei[e], col = ei[NE + e];
            int r0 = atomicAdd(&deg[row], 1);
            int r1 = atomicAdd(&deg[NN + col], 1);
            rank[e] = make_ushort2((ushort)r0, (ushort)r1);
        }
        return;                        // block-uniform exit before any __syncthreads
    }

    // ---- GEMM partition ----
    const int n0 = (bx >> 1) * 128;
    const int w  = bx & 1;
    const float* W = w ? Wd : Ws;
    ushort* y = w ? yd : ys;

    // stage x tile (fp32 -> bf16 in-reg); LDS swizzle byte(row,cb) = row*256 + (cb ^ ((row&7)<<4))
    #pragma unroll
    for (int i = 0; i < 4; ++i) {
        int c = i * 512 + tid;                 // 0..2047 chunks of 8 cols
        int row = c >> 4, colb = (c & 15) * 8;
        int rg = min(n0 + row, NN - 1);
        const float* px = x + (size_t)rg * D + colb;
        float4 v0 = *(const float4*)px;
        float4 v1 = *(const float4*)(px + 4);
        bf16x8 o = { (short)f2bf(v0.x), (short)f2bf(v0.y), (short)f2bf(v0.z), (short)f2bf(v0.w),
                     (short)f2bf(v1.x), (short)f2bf(v1.y), (short)f2bf(v1.z), (short)f2bf(v1.w) };
        *(bf16x8*)((char*)xs + row * 256 + (((c & 15) * 16) ^ ((row & 7) << 4))) = o;
    }
    // stage W (fp32 -> bf16 in-reg)
    #pragma unroll
    for (int i = 0; i < 4; ++i) {
        int c = i * 512 + tid;                 // 0..2047
        int row = c >> 4, colb = (c & 15) * 8;
        const float* pw = W + row * D + colb;
        float4 v0 = *(const float4*)pw;
        float4 v1 = *(const float4*)(pw + 4);
        bf16x8 o = { (short)f2bf(v0.x), (short)f2bf(v0.y), (short)f2bf(v0.z), (short)f2bf(v0.w),
                     (short)f2bf(v1.x), (short)f2bf(v1.y), (short)f2bf(v1.z), (short)f2bf(v1.w) };
        *(bf16x8*)((char*)wsh + row * 256 + (((c & 15) * 16) ^ ((row & 7) << 4))) = o;
    }
    __syncthreads();

    const int wv = tid >> 6, l = tid & 63;
    const int wrow = wv * 16;                  // 8 waves x 16 rows
    const int lr = l & 15;
    const int lkb = (l >> 4) * 16;
    f32x4 acc[8] = {};
    #pragma unroll
    for (int ks = 0; ks < 4; ++ks) {
        int kb = ks * 64 + lkb;
        int arow = wrow + lr;
        bf16x8 a = *(const bf16x8*)((const char*)xs + arow * 256 + (kb ^ ((arow & 7) << 4)));
        #pragma unroll
        for (int n = 0; n < 8; ++n) {
            int brow = n * 16 + lr;
            bf16x8 b = *(const bf16x8*)((const char*)wsh + brow * 256 + (kb ^ ((brow & 7) << 4)));
            acc[n] = __builtin_amdgcn_mfma_f32_16x16x32_bf16(a, b, acc[n], 0, 0, 0);
        }
    }
    int rbase = n0 + wrow + (l >> 4) * 4;      // C/D: col = l&15, row = (l>>4)*4 + reg
    #pragma unroll
    for (int r = 0; r < 4; ++r) {
        int row = rbase + r;
        if (row < NN) {
            #pragma unroll
            for (int n = 0; n < 8; ++n)
                y[(size_t)row * D + n * 16 + lr] = f2bf(acc[n][r]);
        }
    }
}

// ---- hierarchical exclusive scan over deg[0..2NN) -> ptr; also emits rinv ----
__global__ __launch_bounds__(256) void k_scan1(const int* __restrict__ deg,
                                               int* __restrict__ ptr, int* __restrict__ bsum,
                                               float* __restrict__ rinv) {
    __shared__ int s[256];
    int t = threadIdx.x;
    int i = blockIdx.x * 256 + t;
    int v = (i < SCAN_N) ? deg[i] : 0;
    s[t] = v;
    __syncthreads();
    #pragma unroll
    for (int off = 1; off < 256; off <<= 1) {
        int add = (t >= off) ? s[t - off] : 0;
        __syncthreads();
        s[t] += add;
        __syncthreads();
    }
    if (i < SCAN_N) {
        ptr[i] = s[t] - v;
        rinv[i] = v > 0 ? rsqrtf((float)v) : 0.f;
    }
    if (t == 255) bsum[blockIdx.x] = s[255];
}

__global__ __launch_bounds__(1024) void k_scan2(int* __restrict__ bsum) {
    __shared__ int s[1024];
    int t = threadIdx.x;
    int v = (t < NB) ? bsum[t] : 0;
    s[t] = v;
    __syncthreads();
    #pragma unroll
    for (int off = 1; off < 1024; off <<= 1) {
        int add = (t >= off) ? s[t - off] : 0;
        __syncthreads();
        s[t] += add;
        __syncthreads();
    }
    if (t < NB) bsum[t] = s[t] - v;
}

__global__ __launch_bounds__(256) void k_scan3(int* __restrict__ ptr, const int* __restrict__ bsum) {
    int i = blockIdx.x * 256 + threadIdx.x;
    if (i < SCAN_N) ptr[i] += bsum[blockIdx.x];
}

// bucket-fill CSR using precomputed ranks (no atomics): entry = (neighbor, bits(w))
__global__ __launch_bounds__(256) void k_fill(const int* __restrict__ ei, const int* __restrict__ ptr,
                                              const float* __restrict__ rinv,
                                              const ushort2* __restrict__ rank,
                                              int2* __restrict__ idx2) {
    int e = blockIdx.x * 256 + threadIdx.x;
    if (e < NE) {
        int row = ei[e], col = ei[NE + e];
        ushort2 rk = rank[e];
        float w = rinv[row] * rinv[NN + col];
        int wb = __float_as_int(w);
        idx2[ptr[row] + rk.x] = make_int2(col, wb);
        idx2[ptr[NN + col] + rk.y] = make_int2(row, wb);
    }
}

// half-wave split gather (round-5/6 proven, byte-identical): lanes 0-31 = ys, 32-63 = yd.
__global__ __launch_bounds__(256) void k_gather(const int* __restrict__ deg, const int* __restrict__ ptr,
                                                const int2* __restrict__ idx2,
                                                const ushort* __restrict__ ys, const ushort* __restrict__ yd,
                                                const float* __restrict__ bs, const float* __restrict__ bd,
                                                float* __restrict__ out) {
    int wid = (blockIdx.x * 256 + threadIdx.x) >> 6;
    if (wid >= NN) return;
    int lane = threadIdx.x & 63;
    int half = lane >> 5;
    int l5 = lane & 31;
    int base = wid + half * NN;
    int s = ptr[base];
    int d = deg[base];
    const ushort* y = half ? yd : ys;
    float coef = half ? C_DST : C_SRC;
    int j = l5 * 4;

    float4 acc = make_float4(0.f, 0.f, 0.f, 0.f);
    int i = 0;
    for (; i + 4 <= d; i += 4) {
        int2 e0 = idx2[s + i];
        int2 e1 = idx2[s + i + 1];
        int2 e2 = idx2[s + i + 2];
        int2 e3 = idx2[s + i + 3];
        uint2 u0 = *(const uint2*)(y + ((size_t)e0.x << 7) + j);
        uint2 u1 = *(const uint2*)(y + ((size_t)e1.x << 7) + j);
        uint2 u2 = *(const uint2*)(y + ((size_t)e2.x << 7) + j);
        uint2 u3 = *(const uint2*)(y + ((size_t)e3.x << 7) + j);
        float w0 = __int_as_float(e0.y);
        float w1 = __int_as_float(e1.y);
        float w2 = __int_as_float(e2.y);
        float w3 = __int_as_float(e3.y);
        acc.x += w0 * bflo(u0.x) + w1 * bflo(u1.x) + w2 * bflo(u2.x) + w3 * bflo(u3.x);
        acc.y += w0 * bfhi(u0.x) + w1 * bfhi(u1.x) + w2 * bfhi(u2.x) + w3 * bfhi(u3.x);
        acc.z += w0 * bflo(u0.y) + w1 * bflo(u1.y) + w2 * bflo(u2.y) + w3 * bflo(u3.y);
        acc.w += w0 * bfhi(u0.y) + w1 * bfhi(u1.y) + w2 * bfhi(u2.y) + w3 * bfhi(u3.y);
    }
    for (; i < d; ++i) {
        int2 e = idx2[s + i];
        uint2 u = *(const uint2*)(y + ((size_t)e.x << 7) + j);
        float w = __int_as_float(e.y);
        acc.x += w * bflo(u.x);
        acc.y += w * bfhi(u.x);
        acc.z += w * bflo(u.y);
        acc.w += w * bfhi(u.y);
    }
    const float* bb = half ? bd : bs;
    float4 bv = *(const float4*)&bb[j];
    acc.x = coef * (acc.x + bv.x);
    acc.y = coef * (acc.y + bv.y);
    acc.z = coef * (acc.z + bv.z);
    acc.w = coef * (acc.w + bv.w);
    acc.x += __shfl_xor(acc.x, 32);
    acc.y += __shfl_xor(acc.y, 32);
    acc.z += __shfl_xor(acc.z, 32);
    acc.w += __shfl_xor(acc.w, 32);
    if (!half) *(float4*)&out[(size_t)wid * D + j] = acc;
}

extern "C" void kernel_launch(void* const* d_in, const int* in_sizes, int n_in,
                              void* d_out, int out_size, void* d_ws, size_t ws_size,
                              hipStream_t stream) {
    const float* x  = (const float*)d_in[0];
    const int*   ei = (const int*)d_in[1];
    const float* Ws = (const float*)d_in[2];
    const float* bs = (const float*)d_in[3];
    const float* Wd = (const float*)d_in[4];
    const float* bd = (const float*)d_in[5];
    float* out = (float*)d_out;

    // workspace layout
    int*     deg  = (int*)d_ws;                  // 2N
    int*     ptr  = deg + SCAN_N;                // 2N
    int*     bsum = ptr + SCAN_N;                // 1024
    ushort2* rank = (ushort2*)(bsum + 1024);     // NE (4B each)
    int2*    idx2 = (int2*)(rank + NE);          // 2E int2
    float*   rinv = (float*)(idx2 + 2 * NE);     // 2N
    ushort*  ysb  = (ushort*)(rinv + SCAN_N);    // NN*D bf16
    ushort*  ydb  = ysb + (size_t)NN * D;        // NN*D bf16

    hipMemsetAsync(deg, 0, SCAN_N * sizeof(int), stream);
    k_main<<<GEMM_BLKS + DEG_BLKS, 512, 0, stream>>>(x, Ws, Wd, ei, deg, rank, ysb, ydb);
    k_scan1<<<NB, 256, 0, stream>>>(deg, ptr, bsum, rinv);
    k_scan2<<<1, 1024, 0, stream>>>(bsum);
    k_scan3<<<NB, 256, 0, stream>>>(ptr, bsum);
    k_fill<<<(NE + 255) / 256, 256, 0, stream>>>(ei, ptr, rinv, rank, idx2);
    k_gather<<<(NN * 64 + 255) / 256, 256, 0, stream>>>(deg, ptr, idx2, ysb, ydb, bs, bd, out);
}

// Round 8
// 174.807 us; speedup vs baseline: 13.0438x; 1.0270x over previous
//
#include <hip/hip_runtime.h>

#define NN 100000
#define NE 600000
#define D  128
#define C_SRC 0.5f   // (1 - alpha)
#define C_DST 0.5f   // alpha
#define SCAN_N (2 * NN)                 // 200000
#define NB ((SCAN_N + 255) / 256)       // 782
#define GEMM_BLKS (2 * ((NN + 127) / 128))   // 1564: 782 tiles x 2 weights
#define PAD_E (2 * NE + SCAN_N * 7)     // padded CSR worst case: 2.6M entries

typedef __attribute__((ext_vector_type(8))) short bf16x8;
typedef __attribute__((ext_vector_type(4))) float f32x4;

__device__ __forceinline__ ushort f2bf(float f) {
    union { float f; unsigned u; } v; v.f = f;
    unsigned r = v.u + 0x7fffu + ((v.u >> 16) & 1u);   // RNE
    return (ushort)(r >> 16);
}
__device__ __forceinline__ float bflo(unsigned u) { return __uint_as_float(u << 16); }
__device__ __forceinline__ float bfhi(unsigned u) { return __uint_as_float(u & 0xffff0000u); }

// degree count + insertion-rank capture (rank IS the CSR slot; no cur[] later)
__global__ __launch_bounds__(512) void k_deg(const int* __restrict__ ei,
                                             int* __restrict__ deg, ushort2* __restrict__ rank) {
    int e = blockIdx.x * 512 + threadIdx.x;
    if (e < NE) {
        int row = ei[e], col = ei[NE + e];
        int r0 = atomicAdd(&deg[row], 1);
        int r1 = atomicAdd(&deg[NN + col], 1);
        rank[e] = make_ushort2((ushort)r0, (ushort)r1);
    }
}

// ys/yd = x @ W^T; one W per block (blockIdx&1), 128-row x tile, fp32->bf16 in staging.
// LDS swizzle: byte(row,cb) = row*256 + (cb ^ ((row&7)<<4))  (write & read sides match)
__global__ __launch_bounds__(512) void k_gemm(const float* __restrict__ x,
                                              const float* __restrict__ Ws,
                                              const float* __restrict__ Wd,
                                              ushort* __restrict__ ys, ushort* __restrict__ yd) {
    __shared__ ushort xs[128 * 128];   // 32 KiB
    __shared__ ushort wsh[128 * 128];  // 32 KiB
    const int tid = threadIdx.x;
    const int n0 = (blockIdx.x >> 1) * 128;
    const int w  = blockIdx.x & 1;
    const float* W = w ? Wd : Ws;
    ushort* y = w ? yd : ys;

    #pragma unroll
    for (int i = 0; i < 4; ++i) {
        int c = i * 512 + tid;                 // 0..2047 chunks of 8 cols
        int row = c >> 4, colb = (c & 15) * 8;
        int rg = min(n0 + row, NN - 1);
        const float* px = x + (size_t)rg * D + colb;
        float4 v0 = *(const float4*)px;
        float4 v1 = *(const float4*)(px + 4);
        bf16x8 o = { (short)f2bf(v0.x), (short)f2bf(v0.y), (short)f2bf(v0.z), (short)f2bf(v0.w),
                     (short)f2bf(v1.x), (short)f2bf(v1.y), (short)f2bf(v1.z), (short)f2bf(v1.w) };
        *(bf16x8*)((char*)xs + row * 256 + (((c & 15) * 16) ^ ((row & 7) << 4))) = o;
    }
    #pragma unroll
    for (int i = 0; i < 4; ++i) {
        int c = i * 512 + tid;
        int row = c >> 4, colb = (c & 15) * 8;
        const float* pw = W + row * D + colb;
        float4 v0 = *(const float4*)pw;
        float4 v1 = *(const float4*)(pw + 4);
        bf16x8 o = { (short)f2bf(v0.x), (short)f2bf(v0.y), (short)f2bf(v0.z), (short)f2bf(v0.w),
                     (short)f2bf(v1.x), (short)f2bf(v1.y), (short)f2bf(v1.z), (short)f2bf(v1.w) };
        *(bf16x8*)((char*)wsh + row * 256 + (((c & 15) * 16) ^ ((row & 7) << 4))) = o;
    }
    __syncthreads();

    const int wv = tid >> 6, l = tid & 63;
    const int wrow = wv * 16;                  // 8 waves x 16 rows
    const int lr = l & 15;
    const int lkb = (l >> 4) * 16;
    f32x4 acc[8] = {};
    #pragma unroll
    for (int ks = 0; ks < 4; ++ks) {
        int kb = ks * 64 + lkb;
        int arow = wrow + lr;
        bf16x8 a = *(const bf16x8*)((const char*)xs + arow * 256 + (kb ^ ((arow & 7) << 4)));
        #pragma unroll
        for (int n = 0; n < 8; ++n) {
            int brow = n * 16 + lr;
            bf16x8 b = *(const bf16x8*)((const char*)wsh + brow * 256 + (kb ^ ((brow & 7) << 4)));
            acc[n] = __builtin_amdgcn_mfma_f32_16x16x32_bf16(a, b, acc[n], 0, 0, 0);
        }
    }
    int rbase = n0 + wrow + (l >> 4) * 4;      // C/D: col = l&15, row = (l>>4)*4 + reg
    #pragma unroll
    for (int r = 0; r < 4; ++r) {
        int row = rbase + r;
        if (row < NN) {
            #pragma unroll
            for (int n = 0; n < 8; ++n)
                y[(size_t)row * D + n * 16 + lr] = f2bf(acc[n][r]);
        }
    }
}

// ---- hierarchical exclusive scan over PADDED degrees ((deg+7)&~7) -> ptr; emits rinv ----
__global__ __launch_bounds__(256) void k_scan1(const int* __restrict__ deg,
                                               int* __restrict__ ptr, int* __restrict__ bsum,
                                               float* __restrict__ rinv) {
    __shared__ int s[256];
    int t = threadIdx.x;
    int i = blockIdx.x * 256 + t;
    int v = (i < SCAN_N) ? deg[i] : 0;
    int pv = (v + 7) & ~7;
    s[t] = pv;
    __syncthreads();
    #pragma unroll
    for (int off = 1; off < 256; off <<= 1) {
        int add = (t >= off) ? s[t - off] : 0;
        __syncthreads();
        s[t] += add;
        __syncthreads();
    }
    if (i < SCAN_N) {
        ptr[i] = s[t] - pv;
        rinv[i] = v > 0 ? rsqrtf((float)v) : 0.f;
    }
    if (t == 255) bsum[blockIdx.x] = s[255];
}

__global__ __launch_bounds__(1024) void k_scan2(int* __restrict__ bsum) {
    __shared__ int s[1024];
    int t = threadIdx.x;
    int v = (t < NB) ? bsum[t] : 0;
    s[t] = v;
    __syncthreads();
    #pragma unroll
    for (int off = 1; off < 1024; off <<= 1) {
        int add = (t >= off) ? s[t - off] : 0;
        __syncthreads();
        s[t] += add;
        __syncthreads();
    }
    if (t < NB) bsum[t] = s[t] - v;
}

__global__ __launch_bounds__(256) void k_scan3(int* __restrict__ ptr, const int* __restrict__ bsum) {
    int i = blockIdx.x * 256 + threadIdx.x;
    if (i < SCAN_N) ptr[i] += bsum[blockIdx.x];
}

// bucket-fill CSR using precomputed ranks (no atomics). Pad slots stay 0 from memset
// (int2(0, 0.0f) == 8 zero bytes == zero-weight edge to node 0).
__global__ __launch_bounds__(256) void k_fill(const int* __restrict__ ei, const int* __restrict__ ptr,
                                              const float* __restrict__ rinv,
                                              const ushort2* __restrict__ rank,
                                              int2* __restrict__ idx2) {
    int e = blockIdx.x * 256 + threadIdx.x;
    if (e < NE) {
        int row = ei[e], col = ei[NE + e];
        ushort2 rk = rank[e];
        float w = rinv[row] * rinv[NN + col];
        int wb = __float_as_int(w);
        idx2[ptr[row] + rk.x] = make_int2(col, wb);
        idx2[ptr[NN + col] + rk.y] = make_int2(row, wb);
    }
}

// half-wave split gather, branchless ILP-8 over padded segments: lanes 0-31 = ys, 32-63 = yd.
__global__ __launch_bounds__(256) void k_gather(const int* __restrict__ deg, const int* __restrict__ ptr,
                                                const int2* __restrict__ idx2,
                                                const ushort* __restrict__ ys, const ushort* __restrict__ yd,
                                                const float* __restrict__ bs, const float* __restrict__ bd,
                                                float* __restrict__ out) {
    int wid = (blockIdx.x * 256 + threadIdx.x) >> 6;
    if (wid >= NN) return;
    int lane = threadIdx.x & 63;
    int half = lane >> 5;
    int l5 = lane & 31;
    int base = wid + half * NN;
    int s = ptr[base];
    int pd = (deg[base] + 7) & ~7;
    const ushort* y = half ? yd : ys;
    float coef = half ? C_DST : C_SRC;
    int j = l5 * 4;

    float4 acc = make_float4(0.f, 0.f, 0.f, 0.f);
    for (int i = 0; i < pd; i += 8) {
        int2 e[8];
        #pragma unroll
        for (int k = 0; k < 8; ++k) e[k] = idx2[s + i + k];
        uint2 u[8];
        #pragma unroll
        for (int k = 0; k < 8; ++k) u[k] = *(const uint2*)(y + ((size_t)e[k].x << 7) + j);
        #pragma unroll
        for (int k = 0; k < 8; ++k) {
            float w = __int_as_float(e[k].y);
            acc.x += w * bflo(u[k].x);
            acc.y += w * bfhi(u[k].x);
            acc.z += w * bflo(u[k].y);
            acc.w += w * bfhi(u[k].y);
        }
    }
    const float* bb = half ? bd : bs;
    float4 bv = *(const float4*)&bb[j];
    acc.x = coef * (acc.x + bv.x);
    acc.y = coef * (acc.y + bv.y);
    acc.z = coef * (acc.z + bv.z);
    acc.w = coef * (acc.w + bv.w);
    acc.x += __shfl_xor(acc.x, 32);
    acc.y += __shfl_xor(acc.y, 32);
    acc.z += __shfl_xor(acc.z, 32);
    acc.w += __shfl_xor(acc.w, 32);
    if (!half) *(float4*)&out[(size_t)wid * D + j] = acc;
}

extern "C" void kernel_launch(void* const* d_in, const int* in_sizes, int n_in,
                              void* d_out, int out_size, void* d_ws, size_t ws_size,
                              hipStream_t stream) {
    const float* x  = (const float*)d_in[0];
    const int*   ei = (const int*)d_in[1];
    const float* Ws = (const float*)d_in[2];
    const float* bs = (const float*)d_in[3];
    const float* Wd = (const float*)d_in[4];
    const float* bd = (const float*)d_in[5];
    float* out = (float*)d_out;

    // workspace layout (deg and idx2 adjacent -> single zeroing memset)
    int*     deg  = (int*)d_ws;                  // 2N ints
    int2*    idx2 = (int2*)(deg + SCAN_N);       // PAD_E entries (20.8 MB)
    int*     ptr  = (int*)(idx2 + PAD_E);        // 2N
    int*     bsum = ptr + SCAN_N;                // 1024
    ushort2* rank = (ushort2*)(bsum + 1024);     // NE
    float*   rinv = (float*)(rank + NE);         // 2N
    ushort*  ysb  = (ushort*)(rinv + SCAN_N);    // NN*D bf16
    ushort*  ydb  = ysb + (size_t)NN * D;        // NN*D bf16

    hipMemsetAsync(deg, 0, SCAN_N * sizeof(int) + (size_t)PAD_E * sizeof(int2), stream);
    k_deg<<<(NE + 511) / 512, 512, 0, stream>>>(ei, deg, rank);
    k_gemm<<<GEMM_BLKS, 512, 0, stream>>>(x, Ws, Wd, ysb, ydb);
    k_scan1<<<NB, 256, 0, stream>>>(deg, ptr, bsum, rinv);
    k_scan2<<<1, 1024, 0, stream>>>(bsum);
    k_scan3<<<NB, 256, 0, stream>>>(ptr, bsum);
    k_fill<<<(NE + 255) / 256, 256, 0, stream>>>(ei, ptr, rinv, rank, idx2);
    k_gather<<<(NN * 64 + 255) / 256, 256, 0, stream>>>(deg, ptr, idx2, ysb, ydb, bs, bd, out);
}

// Round 9
// 169.330 us; speedup vs baseline: 13.4657x; 1.0323x over previous
//
#include <hip/hip_runtime.h>

#define NN 100000
#define NE 600000
#define D  128
#define C_SRC 0.5f   // (1 - alpha)
#define C_DST 0.5f   // alpha
#define SCAN_N (2 * NN)                 // 200000
#define NB ((SCAN_N + 255) / 256)       // 782
#define GEMM_BLKS (2 * ((NN + 127) / 128))   // 1564: 782 tiles x 2 weights
#define PAD_E (2 * NE + SCAN_N * 7)     // padded CSR worst case: 2.6M entries (4B each)

typedef __attribute__((ext_vector_type(8))) short bf16x8;
typedef __attribute__((ext_vector_type(4))) float f32x4;
typedef __attribute__((ext_vector_type(2))) float f32x2;

__device__ __forceinline__ ushort f2bf(float f) {
    union { float f; unsigned u; } v; v.f = f;
    unsigned r = v.u + 0x7fffu + ((v.u >> 16) & 1u);   // RNE
    return (ushort)(r >> 16);
}
__device__ __forceinline__ unsigned cvtpk(float lo, float hi) {   // [hi|lo] packed bf16, RNE
    unsigned r;
    asm("v_cvt_pk_bf16_f32 %0, %1, %2" : "=v"(r) : "v"(lo), "v"(hi));
    return r;
}
__device__ __forceinline__ float bflo(unsigned u) { return __uint_as_float(u << 16); }
__device__ __forceinline__ float bfhi(unsigned u) { return __uint_as_float(u & 0xffff0000u); }

// degree count + insertion-rank capture (rank IS the CSR slot; no cur[] later)
__global__ __launch_bounds__(512) void k_deg(const int* __restrict__ ei,
                                             int* __restrict__ deg, ushort2* __restrict__ rank) {
    int e = blockIdx.x * 512 + threadIdx.x;
    if (e < NE) {
        int row = ei[e], col = ei[NE + e];
        int r0 = atomicAdd(&deg[row], 1);
        int r1 = atomicAdd(&deg[NN + col], 1);
        rank[e] = make_ushort2((ushort)r0, (ushort)r1);
    }
}

// ys/yd = x @ W^T; one W per block (blockIdx&1), 128-row x tile, fp32->bf16 via v_cvt_pk.
// LDS swizzle: byte(row,cb) = row*256 + (cb ^ ((row&7)<<4))  (write & read sides match)
__global__ __launch_bounds__(512) void k_gemm(const float* __restrict__ x,
                                              const float* __restrict__ Ws,
                                              const float* __restrict__ Wd,
                                              ushort* __restrict__ ys, ushort* __restrict__ yd) {
    __shared__ ushort xs[128 * 128];   // 32 KiB
    __shared__ ushort wsh[128 * 128];  // 32 KiB
    const int tid = threadIdx.x;
    const int n0 = (blockIdx.x >> 1) * 128;
    const int w  = blockIdx.x & 1;
    const float* W = w ? Wd : Ws;
    ushort* y = w ? yd : ys;

    #pragma unroll
    for (int i = 0; i < 4; ++i) {
        int c = i * 512 + tid;                 // 0..2047 chunks of 8 cols
        int row = c >> 4, colb = (c & 15) * 8;
        int rg = min(n0 + row, NN - 1);
        const float* px = x + (size_t)rg * D + colb;
        float4 v0 = *(const float4*)px;
        float4 v1 = *(const float4*)(px + 4);
        uint4 o = { cvtpk(v0.x, v0.y), cvtpk(v0.z, v0.w), cvtpk(v1.x, v1.y), cvtpk(v1.z, v1.w) };
        *(uint4*)((char*)xs + row * 256 + (((c & 15) * 16) ^ ((row & 7) << 4))) = o;
    }
    #pragma unroll
    for (int i = 0; i < 4; ++i) {
        int c = i * 512 + tid;
        int row = c >> 4, colb = (c & 15) * 8;
        const float* pw = W + row * D + colb;
        float4 v0 = *(const float4*)pw;
        float4 v1 = *(const float4*)(pw + 4);
        uint4 o = { cvtpk(v0.x, v0.y), cvtpk(v0.z, v0.w), cvtpk(v1.x, v1.y), cvtpk(v1.z, v1.w) };
        *(uint4*)((char*)wsh + row * 256 + (((c & 15) * 16) ^ ((row & 7) << 4))) = o;
    }
    __syncthreads();

    const int wv = tid >> 6, l = tid & 63;
    const int wrow = wv * 16;                  // 8 waves x 16 rows
    const int lr = l & 15;
    const int lkb = (l >> 4) * 16;
    f32x4 acc[8] = {};
    #pragma unroll
    for (int ks = 0; ks < 4; ++ks) {
        int kb = ks * 64 + lkb;
        int arow = wrow + lr;
        bf16x8 a = *(const bf16x8*)((const char*)xs + arow * 256 + (kb ^ ((arow & 7) << 4)));
        #pragma unroll
        for (int n = 0; n < 8; ++n) {
            int brow = n * 16 + lr;
            bf16x8 b = *(const bf16x8*)((const char*)wsh + brow * 256 + (kb ^ ((brow & 7) << 4)));
            acc[n] = __builtin_amdgcn_mfma_f32_16x16x32_bf16(a, b, acc[n], 0, 0, 0);
        }
    }
    int rbase = n0 + wrow + (l >> 4) * 4;      // C/D: col = l&15, row = (l>>4)*4 + reg
    #pragma unroll
    for (int r = 0; r < 4; ++r) {
        int row = rbase + r;
        if (row < NN) {
            #pragma unroll
            for (int n = 0; n < 8; n += 2) {
                unsigned p = cvtpk(acc[n][r], acc[n + 1][r]);
                y[(size_t)row * D + n * 16 + lr]       = (ushort)p;
                y[(size_t)row * D + (n + 1) * 16 + lr] = (ushort)(p >> 16);
            }
        }
    }
}

// ---- hierarchical exclusive scan over PADDED degrees ((deg+7)&~7) -> ptr; emits rinv ----
__global__ __launch_bounds__(256) void k_scan1(const int* __restrict__ deg,
                                               int* __restrict__ ptr, int* __restrict__ bsum,
                                               float* __restrict__ rinv) {
    __shared__ int s[256];
    int t = threadIdx.x;
    int i = blockIdx.x * 256 + t;
    int v = (i < SCAN_N) ? deg[i] : 0;
    int pv = (v + 7) & ~7;
    s[t] = pv;
    __syncthreads();
    #pragma unroll
    for (int off = 1; off < 256; off <<= 1) {
        int add = (t >= off) ? s[t - off] : 0;
        __syncthreads();
        s[t] += add;
        __syncthreads();
    }
    if (i < SCAN_N) {
        ptr[i] = s[t] - pv;
        rinv[i] = v > 0 ? rsqrtf((float)v) : 0.f;
    }
    if (t == 255) bsum[blockIdx.x] = s[255];
}

__global__ __launch_bounds__(1024) void k_scan2(int* __restrict__ bsum) {
    __shared__ int s[1024];
    int t = threadIdx.x;
    int v = (t < NB) ? bsum[t] : 0;
    s[t] = v;
    __syncthreads();
    #pragma unroll
    for (int off = 1; off < 1024; off <<= 1) {
        int add = (t >= off) ? s[t - off] : 0;
        __syncthreads();
        s[t] += add;
        __syncthreads();
    }
    if (t < NB) bsum[t] = s[t] - v;
}

__global__ __launch_bounds__(256) void k_scan3(int* __restrict__ ptr, const int* __restrict__ bsum) {
    int i = blockIdx.x * 256 + threadIdx.x;
    if (i < SCAN_N) ptr[i] += bsum[blockIdx.x];
}

// bucket-fill CSR, packed 4B entries: (bf16bits(w) << 17) | node.  Pad slots stay 0 from
// memset (node 0, weight +0.0f — a valid zero-weight edge).
__global__ __launch_bounds__(256) void k_fill(const int* __restrict__ ei, const int* __restrict__ ptr,
                                              const float* __restrict__ rinv,
                                              const ushort2* __restrict__ rank,
                                              unsigned* __restrict__ idx) {
    int e = blockIdx.x * 256 + threadIdx.x;
    if (e < NE) {
        int row = ei[e], col = ei[NE + e];
        ushort2 rk = rank[e];
        float w = rinv[row] * rinv[NN + col];
        unsigned wb = (unsigned)f2bf(w) << 17;       // w in (0,1] -> sign bit 0, fits 15 bits
        idx[ptr[row] + rk.x]      = wb | (unsigned)col;
        idx[ptr[NN + col] + rk.y] = wb | (unsigned)row;
    }
}

// half-wave split gather, branchless ILP-8 over padded segments: lanes 0-31 = ys, 32-63 = yd.
__global__ __launch_bounds__(256) void k_gather(const int* __restrict__ deg, const int* __restrict__ ptr,
                                                const unsigned* __restrict__ idx,
                                                const ushort* __restrict__ ys, const ushort* __restrict__ yd,
                                                const float* __restrict__ bs, const float* __restrict__ bd,
                                                float* __restrict__ out) {
    int wid = (blockIdx.x * 256 + threadIdx.x) >> 6;
    if (wid >= NN) return;
    int lane = threadIdx.x & 63;
    int half = lane >> 5;
    int l5 = lane & 31;
    int base = wid + half * NN;
    int s = ptr[base];
    int pd = (deg[base] + 7) & ~7;
    const ushort* y = half ? yd : ys;
    float coef = half ? C_DST : C_SRC;
    int j = l5 * 4;

    f32x2 a01 = {0.f, 0.f}, a23 = {0.f, 0.f};
    for (int i = 0; i < pd; i += 8) {
        unsigned e[8];
        #pragma unroll
        for (int k = 0; k < 8; ++k) e[k] = idx[s + i + k];
        uint2 u[8];
        #pragma unroll
        for (int k = 0; k < 8; ++k)
            u[k] = *(const uint2*)(y + ((size_t)(e[k] & 0x1FFFFu) << 7) + j);
        #pragma unroll
        for (int k = 0; k < 8; ++k) {
            float w = __uint_as_float((e[k] >> 17) << 16);
            f32x2 w2 = {w, w};
            f32x2 v01 = {bflo(u[k].x), bfhi(u[k].x)};
            f32x2 v23 = {bflo(u[k].y), bfhi(u[k].y)};
            a01 += w2 * v01;
            a23 += w2 * v23;
        }
    }
    const float* bb = half ? bd : bs;
    float4 bv = *(const float4*)&bb[j];
    float4 acc;
    acc.x = coef * (a01.x + bv.x);
    acc.y = coef * (a01.y + bv.y);
    acc.z = coef * (a23.x + bv.z);
    acc.w = coef * (a23.y + bv.w);
    acc.x += __shfl_xor(acc.x, 32);
    acc.y += __shfl_xor(acc.y, 32);
    acc.z += __shfl_xor(acc.z, 32);
    acc.w += __shfl_xor(acc.w, 32);
    if (!half) *(float4*)&out[(size_t)wid * D + j] = acc;
}

extern "C" void kernel_launch(void* const* d_in, const int* in_sizes, int n_in,
                              void* d_out, int out_size, void* d_ws, size_t ws_size,
                              hipStream_t stream) {
    const float* x  = (const float*)d_in[0];
    const int*   ei = (const int*)d_in[1];
    const float* Ws = (const float*)d_in[2];
    const float* bs = (const float*)d_in[3];
    const float* Wd = (const float*)d_in[4];
    const float* bd = (const float*)d_in[5];
    float* out = (float*)d_out;

    // workspace layout (deg and idx adjacent -> single zeroing memset)
    int*      deg  = (int*)d_ws;                  // 2N ints
    unsigned* idx  = (unsigned*)(deg + SCAN_N);   // PAD_E packed entries (10.4 MB)
    int*      ptr  = (int*)(idx + PAD_E);         // 2N
    int*      bsum = ptr + SCAN_N;                // 1024
    ushort2*  rank = (ushort2*)(bsum + 1024);     // NE
    float*    rinv = (float*)(rank + NE);         // 2N
    ushort*   ysb  = (ushort*)(rinv + SCAN_N);    // NN*D bf16
    ushort*   ydb  = ysb + (size_t)NN * D;        // NN*D bf16

    hipMemsetAsync(deg, 0, (SCAN_N + PAD_E) * sizeof(int), stream);
    k_deg<<<(NE + 511) / 512, 512, 0, stream>>>(ei, deg, rank);
    k_gemm<<<GEMM_BLKS, 512, 0, stream>>>(x, Ws, Wd, ysb, ydb);
    k_scan1<<<NB, 256, 0, stream>>>(deg, ptr, bsum, rinv);
    k_scan2<<<1, 1024, 0, stream>>>(bsum);
    k_scan3<<<NB, 256, 0, stream>>>(ptr, bsum);
    k_fill<<<(NE + 255) / 256, 256, 0, stream>>>(ei, ptr, rinv, rank, idx);
    k_gather<<<(NN * 64 + 255) / 256, 256, 0, stream>>>(deg, ptr, idx, ysb, ydb, bs, bd, out);
}